// Round 1
// baseline (1542.933 us; speedup 1.0000x reference)
//
#include <hip/hip_runtime.h>

#define NNODES 100000
#define NEDGES 1600000
#define DIM 64

// ---------------- scatter: agg[dst] += x[src], 16 threads per edge ----------
__global__ __launch_bounds__(256) void scatter_kernel(
    const float* __restrict__ x, const int* __restrict__ ei,
    float* __restrict__ agg) {
  int tid = blockIdx.x * 256 + threadIdx.x;   // E*16 threads exactly
  int e = tid >> 4;
  int part = tid & 15;
  int s = ei[e];
  int d = ei[NEDGES + e];
  const float4* xr = (const float4*)(x + (size_t)s * DIM);
  float4 v = xr[part];
  float* a = agg + (size_t)d * DIM + part * 4;
  atomicAdd(a + 0, v.x);
  atomicAdd(a + 1, v.y);
  atomicAdd(a + 2, v.z);
  atomicAdd(a + 3, v.w);
}

// ---------------- fused1: h1 = ((1+eps)*x + agg) @ W1 + b1 (in-place on agg)
__global__ __launch_bounds__(256) void fused1_kernel(
    const float* __restrict__ x, float* __restrict__ h1,
    const float* __restrict__ W1, const float* __restrict__ b1,
    const float* __restrict__ epsp, int N) {
  __shared__ float Ws[DIM * DIM];
  __shared__ float bs[DIM];
  for (int t = threadIdx.x; t < DIM * DIM / 4; t += 256)
    ((float4*)Ws)[t] = ((const float4*)W1)[t];
  if (threadIdx.x < DIM / 4)
    ((float4*)bs)[threadIdx.x] = ((const float4*)b1)[threadIdx.x];
  __syncthreads();
  int i = blockIdx.x * 256 + threadIdx.x;
  if (i >= N) return;
  float onep = 1.0f + epsp[0];
  float h[DIM];
  const float4* xr = (const float4*)(x + (size_t)i * DIM);
  float4* ar = (float4*)(h1 + (size_t)i * DIM);
#pragma unroll
  for (int k4 = 0; k4 < 16; ++k4) {
    float4 a = xr[k4];
    float4 g = ar[k4];
    h[k4 * 4 + 0] = fmaf(onep, a.x, g.x);
    h[k4 * 4 + 1] = fmaf(onep, a.y, g.y);
    h[k4 * 4 + 2] = fmaf(onep, a.z, g.z);
    h[k4 * 4 + 3] = fmaf(onep, a.w, g.w);
  }
#pragma unroll 1
  for (int jt = 0; jt < DIM; jt += 16) {
    float acc[16];
#pragma unroll
    for (int q = 0; q < 4; ++q) {
      float4 b = ((const float4*)&bs[jt])[q];
      acc[q * 4 + 0] = b.x;
      acc[q * 4 + 1] = b.y;
      acc[q * 4 + 2] = b.z;
      acc[q * 4 + 3] = b.w;
    }
#pragma unroll
    for (int k = 0; k < DIM; ++k) {
      float hk = h[k];
      const float4* wr = (const float4*)&Ws[k * DIM + jt];
#pragma unroll
      for (int q = 0; q < 4; ++q) {
        float4 w = wr[q];
        acc[q * 4 + 0] = fmaf(hk, w.x, acc[q * 4 + 0]);
        acc[q * 4 + 1] = fmaf(hk, w.y, acc[q * 4 + 1]);
        acc[q * 4 + 2] = fmaf(hk, w.z, acc[q * 4 + 2]);
        acc[q * 4 + 3] = fmaf(hk, w.w, acc[q * 4 + 3]);
      }
    }
    float4* orow = (float4*)(h1 + (size_t)i * DIM + jt);
#pragma unroll
    for (int q = 0; q < 4; ++q)
      orow[q] = make_float4(acc[q * 4 + 0], acc[q * 4 + 1],
                            acc[q * 4 + 2], acc[q * 4 + 3]);
  }
}

// ---------------- BN stats: per-column sum and sumsq over N rows ------------
__global__ __launch_bounds__(256) void stats_kernel(
    const float* __restrict__ h1, float* __restrict__ sums,
    float* __restrict__ sumsq, int N) {
  int j = threadIdx.x & 63;
  int rsub = threadIdx.x >> 6;  // 0..3
  float s = 0.0f, q = 0.0f;
  for (int r = blockIdx.x * 4 + rsub; r < N; r += gridDim.x * 4) {
    float v = h1[(size_t)r * DIM + j];
    s += v;
    q = fmaf(v, v, q);
  }
  __shared__ float ls[256];
  __shared__ float lq[256];
  ls[threadIdx.x] = s;
  lq[threadIdx.x] = q;
  __syncthreads();
  if (threadIdx.x < 64) {
    s = ls[j] + ls[j + 64] + ls[j + 128] + ls[j + 192];
    q = lq[j] + lq[j + 64] + lq[j + 128] + lq[j + 192];
    atomicAdd(&sums[j], s);
    atomicAdd(&sumsq[j], q);
  }
}

// ---------------- fused2: out = relu(bn(h1)) @ W2 + b2 ----------------------
__global__ __launch_bounds__(256) void fused2_kernel(
    const float* __restrict__ h1, float* __restrict__ out,
    const float* __restrict__ W2, const float* __restrict__ b2,
    const float* __restrict__ gamma, const float* __restrict__ beta,
    const float* __restrict__ sums, const float* __restrict__ sumsq, int N) {
  __shared__ float Ws[DIM * DIM];
  __shared__ float bs[DIM];
  __shared__ float sc_s[DIM];
  __shared__ float sh_s[DIM];
  for (int t = threadIdx.x; t < DIM * DIM / 4; t += 256)
    ((float4*)Ws)[t] = ((const float4*)W2)[t];
  if (threadIdx.x < DIM / 4)
    ((float4*)bs)[threadIdx.x] = ((const float4*)b2)[threadIdx.x];
  if (threadIdx.x >= 64 && threadIdx.x < 128) {
    int j = threadIdx.x - 64;
    float invN = 1.0f / (float)N;
    float m = sums[j] * invN;
    float v = fmaf(-m, m, sumsq[j] * invN);
    float sc = gamma[j] * rsqrtf(v + 1e-5f);
    sc_s[j] = sc;
    sh_s[j] = fmaf(-m, sc, beta[j]);
  }
  __syncthreads();
  int i = blockIdx.x * 256 + threadIdx.x;
  if (i >= N) return;
  float h[DIM];
  const float4* hr = (const float4*)(h1 + (size_t)i * DIM);
#pragma unroll
  for (int k4 = 0; k4 < 16; ++k4) {
    float4 a = hr[k4];
    float4 sc = ((const float4*)sc_s)[k4];
    float4 sh = ((const float4*)sh_s)[k4];
    h[k4 * 4 + 0] = fmaxf(fmaf(a.x, sc.x, sh.x), 0.0f);
    h[k4 * 4 + 1] = fmaxf(fmaf(a.y, sc.y, sh.y), 0.0f);
    h[k4 * 4 + 2] = fmaxf(fmaf(a.z, sc.z, sh.z), 0.0f);
    h[k4 * 4 + 3] = fmaxf(fmaf(a.w, sc.w, sh.w), 0.0f);
  }
#pragma unroll 1
  for (int jt = 0; jt < DIM; jt += 16) {
    float acc[16];
#pragma unroll
    for (int q = 0; q < 4; ++q) {
      float4 b = ((const float4*)&bs[jt])[q];
      acc[q * 4 + 0] = b.x;
      acc[q * 4 + 1] = b.y;
      acc[q * 4 + 2] = b.z;
      acc[q * 4 + 3] = b.w;
    }
#pragma unroll
    for (int k = 0; k < DIM; ++k) {
      float hk = h[k];
      const float4* wr = (const float4*)&Ws[k * DIM + jt];
#pragma unroll
      for (int q = 0; q < 4; ++q) {
        float4 w = wr[q];
        acc[q * 4 + 0] = fmaf(hk, w.x, acc[q * 4 + 0]);
        acc[q * 4 + 1] = fmaf(hk, w.y, acc[q * 4 + 1]);
        acc[q * 4 + 2] = fmaf(hk, w.z, acc[q * 4 + 2]);
        acc[q * 4 + 3] = fmaf(hk, w.w, acc[q * 4 + 3]);
      }
    }
    float4* orow = (float4*)(out + (size_t)i * DIM + jt);
#pragma unroll
    for (int q = 0; q < 4; ++q)
      orow[q] = make_float4(acc[q * 4 + 0], acc[q * 4 + 1],
                            acc[q * 4 + 2], acc[q * 4 + 3]);
  }
}

extern "C" void kernel_launch(void* const* d_in, const int* in_sizes, int n_in,
                              void* d_out, int out_size, void* d_ws, size_t ws_size,
                              hipStream_t stream) {
  (void)in_sizes; (void)n_in; (void)out_size; (void)ws_size;
  const float* x     = (const float*)d_in[0];
  const int*   ei    = (const int*)d_in[1];
  const float* eps   = (const float*)d_in[2];
  const float* W1    = (const float*)d_in[3];
  const float* b1    = (const float*)d_in[4];
  const float* gamma = (const float*)d_in[5];
  const float* beta  = (const float*)d_in[6];
  const float* W2    = (const float*)d_in[7];
  const float* b2    = (const float*)d_in[8];
  float* outp = (float*)d_out;

  const int N = NNODES;
  float* agg   = (float*)d_ws;                 // N*64 f32, reused as h1
  float* sums  = agg + (size_t)N * DIM;        // 64 f32
  float* sumsq = sums + DIM;                   // 64 f32

  hipMemsetAsync(d_ws, 0, ((size_t)N * DIM + 2 * DIM) * sizeof(float), stream);
  scatter_kernel<<<NEDGES * 16 / 256, 256, 0, stream>>>(x, ei, agg);
  fused1_kernel<<<(N + 255) / 256, 256, 0, stream>>>(x, agg, W1, b1, eps, N);
  stats_kernel<<<512, 256, 0, stream>>>(agg, sums, sumsq, N);
  fused2_kernel<<<(N + 255) / 256, 256, 0, stream>>>(agg, outp, W2, b2,
                                                     gamma, beta, sums, sumsq, N);
}

// Round 2
// 449.678 us; speedup vs baseline: 3.4312x; 3.4312x over previous
//
#include <hip/hip_runtime.h>

#define NNODES 100000
#define NEDGES 1600000
#define DIM 64
#define NPAD 100096           // 391 * 256, scan-friendly padding
#define SCAN_BLOCKS 391

// ---------------- degree count: deg[dst]++ ----------------------------------
__global__ __launch_bounds__(256) void degree_kernel(
    const int* __restrict__ ei, int* __restrict__ deg) {
  int e = blockIdx.x * 256 + threadIdx.x;
  int d = ei[NEDGES + e];
  atomicAdd(&deg[d], 1);
}

// ---------------- scan pass A: per-block exclusive scan + block sums --------
__global__ __launch_bounds__(256) void scan_a_kernel(
    const int* __restrict__ deg, int* __restrict__ row_start,
    int* __restrict__ bsum) {
  __shared__ int sd[256];
  int t = threadIdx.x;
  int i = blockIdx.x * 256 + t;
  int v = deg[i];
  sd[t] = v;
  __syncthreads();
  for (int off = 1; off < 256; off <<= 1) {
    int a = (t >= off) ? sd[t - off] : 0;
    __syncthreads();
    sd[t] += a;
    __syncthreads();
  }
  row_start[i] = sd[t] - v;              // exclusive within block
  if (t == 255) bsum[blockIdx.x] = sd[255];
}

// ---------------- scan pass B: exclusive scan of block sums (1 block) -------
__global__ __launch_bounds__(512) void scan_b_kernel(
    const int* __restrict__ bsum, int* __restrict__ boff) {
  __shared__ int sd[512];
  int t = threadIdx.x;
  int v = (t < SCAN_BLOCKS) ? bsum[t] : 0;
  sd[t] = v;
  __syncthreads();
  for (int off = 1; off < 512; off <<= 1) {
    int a = (t >= off) ? sd[t - off] : 0;
    __syncthreads();
    sd[t] += a;
    __syncthreads();
  }
  boff[t] = sd[t] - v;
}

// ---------------- scan pass C: add block offsets, init cursor ---------------
__global__ __launch_bounds__(256) void scan_c_kernel(
    int* __restrict__ row_start, const int* __restrict__ boff,
    int* __restrict__ cursor) {
  int i = blockIdx.x * 256 + threadIdx.x;
  int rs = row_start[i] + boff[blockIdx.x];
  row_start[i] = rs;
  cursor[i] = rs;
}

// ---------------- fill: csr_src[pos] = src ----------------------------------
__global__ __launch_bounds__(256) void fill_kernel(
    const int* __restrict__ ei, int* __restrict__ cursor,
    int* __restrict__ csr_src) {
  int e = blockIdx.x * 256 + threadIdx.x;
  int s = ei[e];
  int d = ei[NEDGES + e];
  int p = atomicAdd(&cursor[d], 1);
  csr_src[p] = s;
}
// after fill: cursor[i] == row_start[i] + deg[i]  (i.e. row end)

// ---------------- gather: agg[i] = sum_{e in row i} x[csr_src[e]] -----------
__global__ __launch_bounds__(256) void gather_kernel(
    const float* __restrict__ x, const int* __restrict__ csr_src,
    const int* __restrict__ row_start, const int* __restrict__ row_end,
    float* __restrict__ agg) {
  int tid = blockIdx.x * 256 + threadIdx.x;   // N*16 threads exactly
  int node = tid >> 4;
  int part = tid & 15;
  int e0 = row_start[node];
  int e1 = row_end[node];
  float4 acc = make_float4(0.f, 0.f, 0.f, 0.f);
  for (int e = e0; e < e1; ++e) {
    int s = csr_src[e];
    float4 v = ((const float4*)(x + (size_t)s * DIM))[part];
    acc.x += v.x; acc.y += v.y; acc.z += v.z; acc.w += v.w;
  }
  ((float4*)(agg + (size_t)node * DIM))[part] = acc;
}

// ---------------- fused1: h1 = ((1+eps)*x + agg) @ W1 + b1 (in-place) -------
__global__ __launch_bounds__(256) void fused1_kernel(
    const float* __restrict__ x, float* __restrict__ h1,
    const float* __restrict__ W1, const float* __restrict__ b1,
    const float* __restrict__ epsp, int N) {
  __shared__ float Ws[DIM * DIM];
  __shared__ float bs[DIM];
  for (int t = threadIdx.x; t < DIM * DIM / 4; t += 256)
    ((float4*)Ws)[t] = ((const float4*)W1)[t];
  if (threadIdx.x < DIM / 4)
    ((float4*)bs)[threadIdx.x] = ((const float4*)b1)[threadIdx.x];
  __syncthreads();
  int i = blockIdx.x * 256 + threadIdx.x;
  if (i >= N) return;
  float onep = 1.0f + epsp[0];
  float h[DIM];
  const float4* xr = (const float4*)(x + (size_t)i * DIM);
  float4* ar = (float4*)(h1 + (size_t)i * DIM);
#pragma unroll
  for (int k4 = 0; k4 < 16; ++k4) {
    float4 a = xr[k4];
    float4 g = ar[k4];
    h[k4 * 4 + 0] = fmaf(onep, a.x, g.x);
    h[k4 * 4 + 1] = fmaf(onep, a.y, g.y);
    h[k4 * 4 + 2] = fmaf(onep, a.z, g.z);
    h[k4 * 4 + 3] = fmaf(onep, a.w, g.w);
  }
#pragma unroll 1
  for (int jt = 0; jt < DIM; jt += 16) {
    float acc[16];
#pragma unroll
    for (int q = 0; q < 4; ++q) {
      float4 b = ((const float4*)&bs[jt])[q];
      acc[q * 4 + 0] = b.x;
      acc[q * 4 + 1] = b.y;
      acc[q * 4 + 2] = b.z;
      acc[q * 4 + 3] = b.w;
    }
#pragma unroll
    for (int k = 0; k < DIM; ++k) {
      float hk = h[k];
      const float4* wr = (const float4*)&Ws[k * DIM + jt];
#pragma unroll
      for (int q = 0; q < 4; ++q) {
        float4 w = wr[q];
        acc[q * 4 + 0] = fmaf(hk, w.x, acc[q * 4 + 0]);
        acc[q * 4 + 1] = fmaf(hk, w.y, acc[q * 4 + 1]);
        acc[q * 4 + 2] = fmaf(hk, w.z, acc[q * 4 + 2]);
        acc[q * 4 + 3] = fmaf(hk, w.w, acc[q * 4 + 3]);
      }
    }
    float4* orow = (float4*)(h1 + (size_t)i * DIM + jt);
#pragma unroll
    for (int q = 0; q < 4; ++q)
      orow[q] = make_float4(acc[q * 4 + 0], acc[q * 4 + 1],
                            acc[q * 4 + 2], acc[q * 4 + 3]);
  }
}

// ---------------- BN stats: per-column sum and sumsq over N rows ------------
__global__ __launch_bounds__(256) void stats_kernel(
    const float* __restrict__ h1, float* __restrict__ sums,
    float* __restrict__ sumsq, int N) {
  int j = threadIdx.x & 63;
  int rsub = threadIdx.x >> 6;  // 0..3
  float s = 0.0f, q = 0.0f;
  for (int r = blockIdx.x * 4 + rsub; r < N; r += gridDim.x * 4) {
    float v = h1[(size_t)r * DIM + j];
    s += v;
    q = fmaf(v, v, q);
  }
  __shared__ float ls[256];
  __shared__ float lq[256];
  ls[threadIdx.x] = s;
  lq[threadIdx.x] = q;
  __syncthreads();
  if (threadIdx.x < 64) {
    s = ls[j] + ls[j + 64] + ls[j + 128] + ls[j + 192];
    q = lq[j] + lq[j + 64] + lq[j + 128] + lq[j + 192];
    atomicAdd(&sums[j], s);
    atomicAdd(&sumsq[j], q);
  }
}

// ---------------- fused2: out = relu(bn(h1)) @ W2 + b2 ----------------------
__global__ __launch_bounds__(256) void fused2_kernel(
    const float* __restrict__ h1, float* __restrict__ out,
    const float* __restrict__ W2, const float* __restrict__ b2,
    const float* __restrict__ gamma, const float* __restrict__ beta,
    const float* __restrict__ sums, const float* __restrict__ sumsq, int N) {
  __shared__ float Ws[DIM * DIM];
  __shared__ float bs[DIM];
  __shared__ float sc_s[DIM];
  __shared__ float sh_s[DIM];
  for (int t = threadIdx.x; t < DIM * DIM / 4; t += 256)
    ((float4*)Ws)[t] = ((const float4*)W2)[t];
  if (threadIdx.x < DIM / 4)
    ((float4*)bs)[threadIdx.x] = ((const float4*)b2)[threadIdx.x];
  if (threadIdx.x >= 64 && threadIdx.x < 128) {
    int j = threadIdx.x - 64;
    float invN = 1.0f / (float)N;
    float m = sums[j] * invN;
    float v = fmaf(-m, m, sumsq[j] * invN);
    float sc = gamma[j] * rsqrtf(v + 1e-5f);
    sc_s[j] = sc;
    sh_s[j] = fmaf(-m, sc, beta[j]);
  }
  __syncthreads();
  int i = blockIdx.x * 256 + threadIdx.x;
  if (i >= N) return;
  float h[DIM];
  const float4* hr = (const float4*)(h1 + (size_t)i * DIM);
#pragma unroll
  for (int k4 = 0; k4 < 16; ++k4) {
    float4 a = hr[k4];
    float4 sc = ((const float4*)sc_s)[k4];
    float4 sh = ((const float4*)sh_s)[k4];
    h[k4 * 4 + 0] = fmaxf(fmaf(a.x, sc.x, sh.x), 0.0f);
    h[k4 * 4 + 1] = fmaxf(fmaf(a.y, sc.y, sh.y), 0.0f);
    h[k4 * 4 + 2] = fmaxf(fmaf(a.z, sc.z, sh.z), 0.0f);
    h[k4 * 4 + 3] = fmaxf(fmaf(a.w, sc.w, sh.w), 0.0f);
  }
#pragma unroll 1
  for (int jt = 0; jt < DIM; jt += 16) {
    float acc[16];
#pragma unroll
    for (int q = 0; q < 4; ++q) {
      float4 b = ((const float4*)&bs[jt])[q];
      acc[q * 4 + 0] = b.x;
      acc[q * 4 + 1] = b.y;
      acc[q * 4 + 2] = b.z;
      acc[q * 4 + 3] = b.w;
    }
#pragma unroll
    for (int k = 0; k < DIM; ++k) {
      float hk = h[k];
      const float4* wr = (const float4*)&Ws[k * DIM + jt];
#pragma unroll
      for (int q = 0; q < 4; ++q) {
        float4 w = wr[q];
        acc[q * 4 + 0] = fmaf(hk, w.x, acc[q * 4 + 0]);
        acc[q * 4 + 1] = fmaf(hk, w.y, acc[q * 4 + 1]);
        acc[q * 4 + 2] = fmaf(hk, w.z, acc[q * 4 + 2]);
        acc[q * 4 + 3] = fmaf(hk, w.w, acc[q * 4 + 3]);
      }
    }
    float4* orow = (float4*)(out + (size_t)i * DIM + jt);
#pragma unroll
    for (int q = 0; q < 4; ++q)
      orow[q] = make_float4(acc[q * 4 + 0], acc[q * 4 + 1],
                            acc[q * 4 + 2], acc[q * 4 + 3]);
  }
}

extern "C" void kernel_launch(void* const* d_in, const int* in_sizes, int n_in,
                              void* d_out, int out_size, void* d_ws, size_t ws_size,
                              hipStream_t stream) {
  (void)in_sizes; (void)n_in; (void)out_size; (void)ws_size;
  const float* x     = (const float*)d_in[0];
  const int*   ei    = (const int*)d_in[1];
  const float* eps   = (const float*)d_in[2];
  const float* W1    = (const float*)d_in[3];
  const float* b1    = (const float*)d_in[4];
  const float* gamma = (const float*)d_in[5];
  const float* beta  = (const float*)d_in[6];
  const float* W2    = (const float*)d_in[7];
  const float* b2    = (const float*)d_in[8];
  float* outp = (float*)d_out;

  const int N = NNODES;

  // workspace layout
  float* agg      = (float*)d_ws;                    // N*64 f32 (reused as h1)
  float* sums     = agg + (size_t)N * DIM;           // 64 f32
  float* sumsq    = sums + DIM;                      // 64 f32
  int*   deg      = (int*)(sumsq + DIM);             // NPAD int (zeroed)
  int*   row_start= deg + NPAD;                      // NPAD int
  int*   cursor   = row_start + NPAD;                // NPAD int
  int*   bsum     = cursor + NPAD;                   // 512 int
  int*   boff     = bsum + 512;                      // 512 int
  int*   csr_src  = boff + 512;                      // NEDGES int

  // zero: sums(64) + sumsq(64) + deg(NPAD) contiguous
  hipMemsetAsync(sums, 0, (2 * DIM + NPAD) * sizeof(int), stream);

  degree_kernel<<<NEDGES / 256, 256, 0, stream>>>(ei, deg);
  scan_a_kernel<<<SCAN_BLOCKS, 256, 0, stream>>>(deg, row_start, bsum);
  scan_b_kernel<<<1, 512, 0, stream>>>(bsum, boff);
  scan_c_kernel<<<SCAN_BLOCKS, 256, 0, stream>>>(row_start, boff, cursor);
  fill_kernel<<<NEDGES / 256, 256, 0, stream>>>(ei, cursor, csr_src);
  gather_kernel<<<N * 16 / 256, 256, 0, stream>>>(x, csr_src, row_start, cursor, agg);
  fused1_kernel<<<(N + 255) / 256, 256, 0, stream>>>(x, agg, W1, b1, eps, N);
  stats_kernel<<<512, 256, 0, stream>>>(agg, sums, sumsq, N);
  fused2_kernel<<<(N + 255) / 256, 256, 0, stream>>>(agg, outp, W2, b2,
                                                     gamma, beta, sums, sumsq, N);
}

// Round 3
// 414.631 us; speedup vs baseline: 3.7212x; 1.0845x over previous
//
#include <hip/hip_runtime.h>

#define NNODES 100000
#define NEDGES 1600000
#define DIM 64
#define NB 391          // buckets of 256 nodes (dst >> 8)
#define NPB 200         // partition blocks
#define CHUNK 8000      // edges per partition block (NPB * CHUNK == NEDGES)
#define MTOT (NB * NPB) // 78200 histogram entries
#define STAGE_CAP 8192  // max edges per bucket staged in LDS (Poisson(4096), 64 sigma headroom)

// ---------------- P1: per-block bucket histogram ----------------------------
__global__ __launch_bounds__(256) void hist_kernel(
    const int* __restrict__ ei, int* __restrict__ hist) {
  __shared__ int lh[NB];
  for (int b = threadIdx.x; b < NB; b += 256) lh[b] = 0;
  __syncthreads();
  int base = blockIdx.x * CHUNK;
  for (int i = threadIdx.x; i < CHUNK; i += 256) {
    int d = ei[NEDGES + base + i];
    atomicAdd(&lh[d >> 8], 1);
  }
  __syncthreads();
  for (int b = threadIdx.x; b < NB; b += 256)
    hist[b * NPB + blockIdx.x] = lh[b];   // bucket-major for the scan
}

// ---------------- P2: single-block exclusive scan over MTOT entries ---------
__global__ __launch_bounds__(1024) void scan_kernel(int* __restrict__ hist) {
  __shared__ int sd[1024];
  int t = threadIdx.x;
  const int per = (MTOT + 1023) / 1024;   // 77
  int s0 = t * per;
  int s1 = s0 + per; if (s1 > MTOT) s1 = MTOT;
  int sum = 0;
  for (int i = s0; i < s1; ++i) sum += hist[i];
  sd[t] = sum;
  __syncthreads();
  for (int off = 1; off < 1024; off <<= 1) {
    int a = (t >= off) ? sd[t - off] : 0;
    __syncthreads();
    sd[t] += a;
    __syncthreads();
  }
  int run = sd[t] - sum;                  // exclusive prefix of this range
  for (int i = s0; i < s1; ++i) {
    int v = hist[i];
    hist[i] = run;                        // in-place: hist becomes offs
    run += v;
  }
}

// ---------------- P3: partition edges into buckets (packed dlow|src) --------
__global__ __launch_bounds__(256) void partition_kernel(
    const int* __restrict__ ei, const int* __restrict__ offs,
    int* __restrict__ bpart) {
  __shared__ int cur[NB];
  for (int b = threadIdx.x; b < NB; b += 256)
    cur[b] = offs[b * NPB + blockIdx.x];
  __syncthreads();
  int base = blockIdx.x * CHUNK;
  for (int i = threadIdx.x; i < CHUNK; i += 256) {
    int s = ei[base + i];
    int d = ei[NEDGES + base + i];
    int p = atomicAdd(&cur[d >> 8], 1);
    bpart[p] = ((d & 255) << 17) | s;     // src < 2^17, dlow in bits 17..24
  }
}

// ---------------- P4: per-bucket counting sort, coalesced csr flush ---------
__global__ __launch_bounds__(256) void bucket_kernel(
    const int* __restrict__ bpart, const int* __restrict__ offs,
    int* __restrict__ csr_src, int* __restrict__ row_start,
    int* __restrict__ row_end) {
  __shared__ int sd[256];
  __shared__ int cur[256];
  __shared__ int stage[STAGE_CAP];
  int b = blockIdx.x;
  int t = threadIdx.x;
  int base = offs[b * NPB];
  int end = (b == NB - 1) ? NEDGES : offs[(b + 1) * NPB];
  int cnt = end - base;
  sd[t] = 0;
  __syncthreads();
  for (int i = t; i < cnt; i += 256)
    atomicAdd(&sd[bpart[base + i] >> 17], 1);
  __syncthreads();
  int deg = sd[t];
  for (int off = 1; off < 256; off <<= 1) {  // inclusive scan of degrees
    int a = (t >= off) ? sd[t - off] : 0;
    __syncthreads();
    sd[t] += a;
    __syncthreads();
  }
  int excl = sd[t] - deg;
  int node = b * 256 + t;
  if (node < NNODES) {
    row_start[node] = base + excl;
    row_end[node] = base + excl + deg;
  }
  cur[t] = excl;
  __syncthreads();
  for (int i = t; i < cnt; i += 256) {
    int v = bpart[base + i];
    int p = atomicAdd(&cur[v >> 17], 1);
    stage[p] = v & 0x1FFFF;               // LDS scatter, cheap
  }
  __syncthreads();
  for (int i = t; i < cnt; i += 256)
    csr_src[base + i] = stage[i];         // fully coalesced global flush
}

// ---------------- gather: agg[i] = sum_{e in row i} x[csr_src[e]] -----------
__global__ __launch_bounds__(256) void gather_kernel(
    const float* __restrict__ x, const int* __restrict__ csr_src,
    const int* __restrict__ row_start, const int* __restrict__ row_end,
    float* __restrict__ agg) {
  int tid = blockIdx.x * 256 + threadIdx.x;   // N*16 threads exactly
  int node = tid >> 4;
  int part = tid & 15;
  int e0 = row_start[node];
  int e1 = row_end[node];
  float4 acc = make_float4(0.f, 0.f, 0.f, 0.f);
  for (int e = e0; e < e1; ++e) {
    int s = csr_src[e];
    float4 v = ((const float4*)(x + (size_t)s * DIM))[part];
    acc.x += v.x; acc.y += v.y; acc.z += v.z; acc.w += v.w;
  }
  ((float4*)(agg + (size_t)node * DIM))[part] = acc;
}

// ---------------- fused1: h1 = ((1+eps)*x + agg) @ W1 + b1 (in-place) -------
__global__ __launch_bounds__(256) void fused1_kernel(
    const float* __restrict__ x, float* __restrict__ h1,
    const float* __restrict__ W1, const float* __restrict__ b1,
    const float* __restrict__ epsp, int N) {
  __shared__ float Ws[DIM * DIM];
  __shared__ float bs[DIM];
  for (int t = threadIdx.x; t < DIM * DIM / 4; t += 256)
    ((float4*)Ws)[t] = ((const float4*)W1)[t];
  if (threadIdx.x < DIM / 4)
    ((float4*)bs)[threadIdx.x] = ((const float4*)b1)[threadIdx.x];
  __syncthreads();
  int i = blockIdx.x * 256 + threadIdx.x;
  if (i >= N) return;
  float onep = 1.0f + epsp[0];
  float h[DIM];
  const float4* xr = (const float4*)(x + (size_t)i * DIM);
  float4* ar = (float4*)(h1 + (size_t)i * DIM);
#pragma unroll
  for (int k4 = 0; k4 < 16; ++k4) {
    float4 a = xr[k4];
    float4 g = ar[k4];
    h[k4 * 4 + 0] = fmaf(onep, a.x, g.x);
    h[k4 * 4 + 1] = fmaf(onep, a.y, g.y);
    h[k4 * 4 + 2] = fmaf(onep, a.z, g.z);
    h[k4 * 4 + 3] = fmaf(onep, a.w, g.w);
  }
#pragma unroll 1
  for (int jt = 0; jt < DIM; jt += 16) {
    float acc[16];
#pragma unroll
    for (int q = 0; q < 4; ++q) {
      float4 b = ((const float4*)&bs[jt])[q];
      acc[q * 4 + 0] = b.x;
      acc[q * 4 + 1] = b.y;
      acc[q * 4 + 2] = b.z;
      acc[q * 4 + 3] = b.w;
    }
#pragma unroll
    for (int k = 0; k < DIM; ++k) {
      float hk = h[k];
      const float4* wr = (const float4*)&Ws[k * DIM + jt];
#pragma unroll
      for (int q = 0; q < 4; ++q) {
        float4 w = wr[q];
        acc[q * 4 + 0] = fmaf(hk, w.x, acc[q * 4 + 0]);
        acc[q * 4 + 1] = fmaf(hk, w.y, acc[q * 4 + 1]);
        acc[q * 4 + 2] = fmaf(hk, w.z, acc[q * 4 + 2]);
        acc[q * 4 + 3] = fmaf(hk, w.w, acc[q * 4 + 3]);
      }
    }
    float4* orow = (float4*)(h1 + (size_t)i * DIM + jt);
#pragma unroll
    for (int q = 0; q < 4; ++q)
      orow[q] = make_float4(acc[q * 4 + 0], acc[q * 4 + 1],
                            acc[q * 4 + 2], acc[q * 4 + 3]);
  }
}

// ---------------- BN stats: per-column sum and sumsq over N rows ------------
__global__ __launch_bounds__(256) void stats_kernel(
    const float* __restrict__ h1, float* __restrict__ sums,
    float* __restrict__ sumsq, int N) {
  int j = threadIdx.x & 63;
  int rsub = threadIdx.x >> 6;  // 0..3
  float s = 0.0f, q = 0.0f;
  for (int r = blockIdx.x * 4 + rsub; r < N; r += gridDim.x * 4) {
    float v = h1[(size_t)r * DIM + j];
    s += v;
    q = fmaf(v, v, q);
  }
  __shared__ float ls[256];
  __shared__ float lq[256];
  ls[threadIdx.x] = s;
  lq[threadIdx.x] = q;
  __syncthreads();
  if (threadIdx.x < 64) {
    s = ls[j] + ls[j + 64] + ls[j + 128] + ls[j + 192];
    q = lq[j] + lq[j + 64] + lq[j + 128] + lq[j + 192];
    atomicAdd(&sums[j], s);
    atomicAdd(&sumsq[j], q);
  }
}

// ---------------- fused2: out = relu(bn(h1)) @ W2 + b2 ----------------------
__global__ __launch_bounds__(256) void fused2_kernel(
    const float* __restrict__ h1, float* __restrict__ out,
    const float* __restrict__ W2, const float* __restrict__ b2,
    const float* __restrict__ gamma, const float* __restrict__ beta,
    const float* __restrict__ sums, const float* __restrict__ sumsq, int N) {
  __shared__ float Ws[DIM * DIM];
  __shared__ float bs[DIM];
  __shared__ float sc_s[DIM];
  __shared__ float sh_s[DIM];
  for (int t = threadIdx.x; t < DIM * DIM / 4; t += 256)
    ((float4*)Ws)[t] = ((const float4*)W2)[t];
  if (threadIdx.x < DIM / 4)
    ((float4*)bs)[threadIdx.x] = ((const float4*)b2)[threadIdx.x];
  if (threadIdx.x >= 64 && threadIdx.x < 128) {
    int j = threadIdx.x - 64;
    float invN = 1.0f / (float)N;
    float m = sums[j] * invN;
    float v = fmaf(-m, m, sumsq[j] * invN);
    float sc = gamma[j] * rsqrtf(v + 1e-5f);
    sc_s[j] = sc;
    sh_s[j] = fmaf(-m, sc, beta[j]);
  }
  __syncthreads();
  int i = blockIdx.x * 256 + threadIdx.x;
  if (i >= N) return;
  float h[DIM];
  const float4* hr = (const float4*)(h1 + (size_t)i * DIM);
#pragma unroll
  for (int k4 = 0; k4 < 16; ++k4) {
    float4 a = hr[k4];
    float4 sc = ((const float4*)sc_s)[k4];
    float4 sh = ((const float4*)sh_s)[k4];
    h[k4 * 4 + 0] = fmaxf(fmaf(a.x, sc.x, sh.x), 0.0f);
    h[k4 * 4 + 1] = fmaxf(fmaf(a.y, sc.y, sh.y), 0.0f);
    h[k4 * 4 + 2] = fmaxf(fmaf(a.z, sc.z, sh.z), 0.0f);
    h[k4 * 4 + 3] = fmaxf(fmaf(a.w, sc.w, sh.w), 0.0f);
  }
#pragma unroll 1
  for (int jt = 0; jt < DIM; jt += 16) {
    float acc[16];
#pragma unroll
    for (int q = 0; q < 4; ++q) {
      float4 b = ((const float4*)&bs[jt])[q];
      acc[q * 4 + 0] = b.x;
      acc[q * 4 + 1] = b.y;
      acc[q * 4 + 2] = b.z;
      acc[q * 4 + 3] = b.w;
    }
#pragma unroll
    for (int k = 0; k < DIM; ++k) {
      float hk = h[k];
      const float4* wr = (const float4*)&Ws[k * DIM + jt];
#pragma unroll
      for (int q = 0; q < 4; ++q) {
        float4 w = wr[q];
        acc[q * 4 + 0] = fmaf(hk, w.x, acc[q * 4 + 0]);
        acc[q * 4 + 1] = fmaf(hk, w.y, acc[q * 4 + 1]);
        acc[q * 4 + 2] = fmaf(hk, w.z, acc[q * 4 + 2]);
        acc[q * 4 + 3] = fmaf(hk, w.w, acc[q * 4 + 3]);
      }
    }
    float4* orow = (float4*)(out + (size_t)i * DIM + jt);
#pragma unroll
    for (int q = 0; q < 4; ++q)
      orow[q] = make_float4(acc[q * 4 + 0], acc[q * 4 + 1],
                            acc[q * 4 + 2], acc[q * 4 + 3]);
  }
}

extern "C" void kernel_launch(void* const* d_in, const int* in_sizes, int n_in,
                              void* d_out, int out_size, void* d_ws, size_t ws_size,
                              hipStream_t stream) {
  (void)in_sizes; (void)n_in; (void)out_size; (void)ws_size;
  const float* x     = (const float*)d_in[0];
  const int*   ei    = (const int*)d_in[1];
  const float* eps   = (const float*)d_in[2];
  const float* W1    = (const float*)d_in[3];
  const float* b1    = (const float*)d_in[4];
  const float* gamma = (const float*)d_in[5];
  const float* beta  = (const float*)d_in[6];
  const float* W2    = (const float*)d_in[7];
  const float* b2    = (const float*)d_in[8];
  float* outp = (float*)d_out;

  const int N = NNODES;

  // workspace layout (~33.1 MB)
  float* agg      = (float*)d_ws;                    // N*64 f32 (reused as h1)
  float* sums     = agg + (size_t)N * DIM;           // 64 f32
  float* sumsq    = sums + DIM;                      // 64 f32
  int*   row_start= (int*)(sumsq + DIM);             // N int
  int*   row_end  = row_start + NNODES;              // N int
  int*   csr_src  = row_end + NNODES;                // NEDGES int
  int*   hist     = csr_src + NEDGES;                // MTOT int (becomes offs)
  int*   bpart    = (int*)agg;                       // NEDGES int, aliases agg
                                                     // (dead before gather writes agg)

  hipMemsetAsync(sums, 0, 2 * DIM * sizeof(float), stream);

  hist_kernel     <<<NPB, 256, 0, stream>>>(ei, hist);
  scan_kernel     <<<1, 1024, 0, stream>>>(hist);
  partition_kernel<<<NPB, 256, 0, stream>>>(ei, hist, bpart);
  bucket_kernel   <<<NB, 256, 0, stream>>>(bpart, hist, csr_src, row_start, row_end);
  gather_kernel   <<<N * 16 / 256, 256, 0, stream>>>(x, csr_src, row_start, row_end, agg);
  fused1_kernel   <<<(N + 255) / 256, 256, 0, stream>>>(x, agg, W1, b1, eps, N);
  stats_kernel    <<<512, 256, 0, stream>>>(agg, sums, sumsq, N);
  fused2_kernel   <<<(N + 255) / 256, 256, 0, stream>>>(agg, outp, W2, b2,
                                                        gamma, beta, sums, sumsq, N);
}

// Round 4
// 301.376 us; speedup vs baseline: 5.1196x; 1.3758x over previous
//
#include <hip/hip_runtime.h>

#define NNODES 100000
#define NEDGES 1600000
#define DIM 64
#define NB 391          // buckets of 256 nodes (dst >> 8)
#define NPB 200         // partition blocks
#define CHUNK 8000      // edges per partition block (NPB * CHUNK == NEDGES)
#define STAGE_CAP 8192  // max edges per bucket staged in LDS (Poisson(4096))

// ---------------- P1: global per-bucket totals ------------------------------
__global__ __launch_bounds__(256) void hist_kernel(
    const int* __restrict__ ei, int* __restrict__ gcount) {
  __shared__ int lh[NB];
  for (int b = threadIdx.x; b < NB; b += 256) lh[b] = 0;
  __syncthreads();
  int base = blockIdx.x * CHUNK;
  for (int i = threadIdx.x; i < CHUNK; i += 256)
    atomicAdd(&lh[ei[NEDGES + base + i] >> 8], 1);
  __syncthreads();
  for (int b = threadIdx.x; b < NB; b += 256) {
    int c = lh[b];
    if (c) atomicAdd(&gcount[b], c);
  }
}

// ---------------- P2: tiny scan of 391 bucket totals ------------------------
__global__ __launch_bounds__(512) void scan_small_kernel(
    const int* __restrict__ gcount, int* __restrict__ bucket_base,
    int* __restrict__ gcursor) {
  __shared__ int sd[512];
  int t = threadIdx.x;
  int v = (t < NB) ? gcount[t] : 0;
  sd[t] = v;
  __syncthreads();
  for (int off = 1; off < 512; off <<= 1) {
    int a = (t >= off) ? sd[t - off] : 0;
    __syncthreads();
    sd[t] += a;
    __syncthreads();
  }
  int excl = sd[t] - v;          // exclusive prefix; t==NB gives total==NEDGES
  bucket_base[t] = excl;
  gcursor[t] = excl;
}

// ---------------- P3: partition edges into buckets (dynamic reservation) ----
__global__ __launch_bounds__(256) void partition_kernel(
    const int* __restrict__ ei, int* __restrict__ gcursor,
    int* __restrict__ bpart) {
  __shared__ int lh[NB];
  __shared__ int cur[NB];
  for (int b = threadIdx.x; b < NB; b += 256) lh[b] = 0;
  __syncthreads();
  int base = blockIdx.x * CHUNK;
  for (int i = threadIdx.x; i < CHUNK; i += 256)
    atomicAdd(&lh[ei[NEDGES + base + i] >> 8], 1);
  __syncthreads();
  for (int b = threadIdx.x; b < NB; b += 256) {
    int c = lh[b];
    cur[b] = c ? atomicAdd(&gcursor[b], c) : 0;   // reserve contiguous run
  }
  __syncthreads();
  for (int i = threadIdx.x; i < CHUNK; i += 256) {
    int s = ei[base + i];
    int d = ei[NEDGES + base + i];
    int p = atomicAdd(&cur[d >> 8], 1);
    bpart[p] = ((d & 255) << 17) | s;   // src < 2^17, dlow in bits 17..24
  }
}

// ---------------- P4: per-bucket counting sort, coalesced csr flush ---------
__global__ __launch_bounds__(256) void bucket_kernel(
    const int* __restrict__ bpart, const int* __restrict__ bucket_base,
    int* __restrict__ csr_src, int* __restrict__ row_start,
    int* __restrict__ row_end) {
  __shared__ int sd[256];
  __shared__ int cur[256];
  __shared__ int stage[STAGE_CAP];
  int b = blockIdx.x;
  int t = threadIdx.x;
  int base = bucket_base[b];
  int end = bucket_base[b + 1];
  int cnt = end - base;
  sd[t] = 0;
  __syncthreads();
  for (int i = t; i < cnt; i += 256)
    atomicAdd(&sd[bpart[base + i] >> 17], 1);
  __syncthreads();
  int deg = sd[t];
  for (int off = 1; off < 256; off <<= 1) {  // inclusive scan of degrees
    int a = (t >= off) ? sd[t - off] : 0;
    __syncthreads();
    sd[t] += a;
    __syncthreads();
  }
  int excl = sd[t] - deg;
  int node = b * 256 + t;
  if (node < NNODES) {
    row_start[node] = base + excl;
    row_end[node] = base + excl + deg;
  }
  cur[t] = excl;
  __syncthreads();
  for (int i = t; i < cnt; i += 256) {
    int v = bpart[base + i];
    int p = atomicAdd(&cur[v >> 17], 1);
    stage[p] = v & 0x1FFFF;               // LDS scatter, cheap
  }
  __syncthreads();
  for (int i = t; i < cnt; i += 256)
    csr_src[base + i] = stage[i];         // fully coalesced global flush
}

// ---------------- gather: agg[i] = sum_{e in row i} x[csr_src[e]] -----------
__global__ __launch_bounds__(256) void gather_kernel(
    const float* __restrict__ x, const int* __restrict__ csr_src,
    const int* __restrict__ row_start, const int* __restrict__ row_end,
    float* __restrict__ agg) {
  int tid = blockIdx.x * 256 + threadIdx.x;   // N*16 threads exactly
  int node = tid >> 4;
  int part = tid & 15;
  int e0 = row_start[node];
  int e1 = row_end[node];
  float4 acc = make_float4(0.f, 0.f, 0.f, 0.f);
  for (int e = e0; e < e1; ++e) {
    int s = csr_src[e];
    float4 v = ((const float4*)(x + (size_t)s * DIM))[part];
    acc.x += v.x; acc.y += v.y; acc.z += v.z; acc.w += v.w;
  }
  ((float4*)(agg + (size_t)node * DIM))[part] = acc;
}

// ---------------- fused1: h1 = ((1+eps)*x + agg) @ W1 + b1 (in-place) -------
__global__ __launch_bounds__(256) void fused1_kernel(
    const float* __restrict__ x, float* __restrict__ h1,
    const float* __restrict__ W1, const float* __restrict__ b1,
    const float* __restrict__ epsp, int N) {
  __shared__ float Ws[DIM * DIM];
  __shared__ float bs[DIM];
  for (int t = threadIdx.x; t < DIM * DIM / 4; t += 256)
    ((float4*)Ws)[t] = ((const float4*)W1)[t];
  if (threadIdx.x < DIM / 4)
    ((float4*)bs)[threadIdx.x] = ((const float4*)b1)[threadIdx.x];
  __syncthreads();
  int i = blockIdx.x * 256 + threadIdx.x;
  if (i >= N) return;
  float onep = 1.0f + epsp[0];
  float h[DIM];
  const float4* xr = (const float4*)(x + (size_t)i * DIM);
  float4* ar = (float4*)(h1 + (size_t)i * DIM);
#pragma unroll
  for (int k4 = 0; k4 < 16; ++k4) {
    float4 a = xr[k4];
    float4 g = ar[k4];
    h[k4 * 4 + 0] = fmaf(onep, a.x, g.x);
    h[k4 * 4 + 1] = fmaf(onep, a.y, g.y);
    h[k4 * 4 + 2] = fmaf(onep, a.z, g.z);
    h[k4 * 4 + 3] = fmaf(onep, a.w, g.w);
  }
#pragma unroll 1
  for (int jt = 0; jt < DIM; jt += 16) {
    float acc[16];
#pragma unroll
    for (int q = 0; q < 4; ++q) {
      float4 b = ((const float4*)&bs[jt])[q];
      acc[q * 4 + 0] = b.x;
      acc[q * 4 + 1] = b.y;
      acc[q * 4 + 2] = b.z;
      acc[q * 4 + 3] = b.w;
    }
#pragma unroll
    for (int k = 0; k < DIM; ++k) {
      float hk = h[k];
      const float4* wr = (const float4*)&Ws[k * DIM + jt];
#pragma unroll
      for (int q = 0; q < 4; ++q) {
        float4 w = wr[q];
        acc[q * 4 + 0] = fmaf(hk, w.x, acc[q * 4 + 0]);
        acc[q * 4 + 1] = fmaf(hk, w.y, acc[q * 4 + 1]);
        acc[q * 4 + 2] = fmaf(hk, w.z, acc[q * 4 + 2]);
        acc[q * 4 + 3] = fmaf(hk, w.w, acc[q * 4 + 3]);
      }
    }
    float4* orow = (float4*)(h1 + (size_t)i * DIM + jt);
#pragma unroll
    for (int q = 0; q < 4; ++q)
      orow[q] = make_float4(acc[q * 4 + 0], acc[q * 4 + 1],
                            acc[q * 4 + 2], acc[q * 4 + 3]);
  }
}

// ---------------- BN stats: per-column sum and sumsq over N rows ------------
__global__ __launch_bounds__(256) void stats_kernel(
    const float* __restrict__ h1, float* __restrict__ sums,
    float* __restrict__ sumsq, int N) {
  int j = threadIdx.x & 63;
  int rsub = threadIdx.x >> 6;  // 0..3
  float s = 0.0f, q = 0.0f;
  for (int r = blockIdx.x * 4 + rsub; r < N; r += gridDim.x * 4) {
    float v = h1[(size_t)r * DIM + j];
    s += v;
    q = fmaf(v, v, q);
  }
  __shared__ float ls[256];
  __shared__ float lq[256];
  ls[threadIdx.x] = s;
  lq[threadIdx.x] = q;
  __syncthreads();
  if (threadIdx.x < 64) {
    s = ls[j] + ls[j + 64] + ls[j + 128] + ls[j + 192];
    q = lq[j] + lq[j + 64] + lq[j + 128] + lq[j + 192];
    atomicAdd(&sums[j], s);
    atomicAdd(&sumsq[j], q);
  }
}

// ---------------- fused2: out = relu(bn(h1)) @ W2 + b2 ----------------------
__global__ __launch_bounds__(256) void fused2_kernel(
    const float* __restrict__ h1, float* __restrict__ out,
    const float* __restrict__ W2, const float* __restrict__ b2,
    const float* __restrict__ gamma, const float* __restrict__ beta,
    const float* __restrict__ sums, const float* __restrict__ sumsq, int N) {
  __shared__ float Ws[DIM * DIM];
  __shared__ float bs[DIM];
  __shared__ float sc_s[DIM];
  __shared__ float sh_s[DIM];
  for (int t = threadIdx.x; t < DIM * DIM / 4; t += 256)
    ((float4*)Ws)[t] = ((const float4*)W2)[t];
  if (threadIdx.x < DIM / 4)
    ((float4*)bs)[threadIdx.x] = ((const float4*)b2)[threadIdx.x];
  if (threadIdx.x >= 64 && threadIdx.x < 128) {
    int j = threadIdx.x - 64;
    float invN = 1.0f / (float)N;
    float m = sums[j] * invN;
    float v = fmaf(-m, m, sumsq[j] * invN);
    float sc = gamma[j] * rsqrtf(v + 1e-5f);
    sc_s[j] = sc;
    sh_s[j] = fmaf(-m, sc, beta[j]);
  }
  __syncthreads();
  int i = blockIdx.x * 256 + threadIdx.x;
  if (i >= N) return;
  float h[DIM];
  const float4* hr = (const float4*)(h1 + (size_t)i * DIM);
#pragma unroll
  for (int k4 = 0; k4 < 16; ++k4) {
    float4 a = hr[k4];
    float4 sc = ((const float4*)sc_s)[k4];
    float4 sh = ((const float4*)sh_s)[k4];
    h[k4 * 4 + 0] = fmaxf(fmaf(a.x, sc.x, sh.x), 0.0f);
    h[k4 * 4 + 1] = fmaxf(fmaf(a.y, sc.y, sh.y), 0.0f);
    h[k4 * 4 + 2] = fmaxf(fmaf(a.z, sc.z, sh.z), 0.0f);
    h[k4 * 4 + 3] = fmaxf(fmaf(a.w, sc.w, sh.w), 0.0f);
  }
#pragma unroll 1
  for (int jt = 0; jt < DIM; jt += 16) {
    float acc[16];
#pragma unroll
    for (int q = 0; q < 4; ++q) {
      float4 b = ((const float4*)&bs[jt])[q];
      acc[q * 4 + 0] = b.x;
      acc[q * 4 + 1] = b.y;
      acc[q * 4 + 2] = b.z;
      acc[q * 4 + 3] = b.w;
    }
#pragma unroll
    for (int k = 0; k < DIM; ++k) {
      float hk = h[k];
      const float4* wr = (const float4*)&Ws[k * DIM + jt];
#pragma unroll
      for (int q = 0; q < 4; ++q) {
        float4 w = wr[q];
        acc[q * 4 + 0] = fmaf(hk, w.x, acc[q * 4 + 0]);
        acc[q * 4 + 1] = fmaf(hk, w.y, acc[q * 4 + 1]);
        acc[q * 4 + 2] = fmaf(hk, w.z, acc[q * 4 + 2]);
        acc[q * 4 + 3] = fmaf(hk, w.w, acc[q * 4 + 3]);
      }
    }
    float4* orow = (float4*)(out + (size_t)i * DIM + jt);
#pragma unroll
    for (int q = 0; q < 4; ++q)
      orow[q] = make_float4(acc[q * 4 + 0], acc[q * 4 + 1],
                            acc[q * 4 + 2], acc[q * 4 + 3]);
  }
}

extern "C" void kernel_launch(void* const* d_in, const int* in_sizes, int n_in,
                              void* d_out, int out_size, void* d_ws, size_t ws_size,
                              hipStream_t stream) {
  (void)in_sizes; (void)n_in; (void)out_size; (void)ws_size;
  const float* x     = (const float*)d_in[0];
  const int*   ei    = (const int*)d_in[1];
  const float* eps   = (const float*)d_in[2];
  const float* W1    = (const float*)d_in[3];
  const float* b1    = (const float*)d_in[4];
  const float* gamma = (const float*)d_in[5];
  const float* beta  = (const float*)d_in[6];
  const float* W2    = (const float*)d_in[7];
  const float* b2    = (const float*)d_in[8];
  float* outp = (float*)d_out;

  const int N = NNODES;

  // workspace layout
  float* agg        = (float*)d_ws;                  // N*64 f32 (reused as h1)
  float* sums       = agg + (size_t)N * DIM;         // 64 f32   (zeroed)
  float* sumsq      = sums + DIM;                    // 64 f32   (zeroed)
  int*   gcount     = (int*)(sumsq + DIM);           // 512 int  (zeroed)
  int*   bucket_base= gcount + 512;                  // 512 int
  int*   gcursor    = bucket_base + 512;             // 512 int
  int*   row_start  = gcursor + 512;                 // N int
  int*   row_end    = row_start + NNODES;            // N int
  int*   csr_src    = row_end + NNODES;              // NEDGES int
  int*   bpart      = (int*)agg;                     // NEDGES int, aliases agg
                                                     // (dead before gather writes agg)

  // zero: sums(64) + sumsq(64) + gcount(512), contiguous
  hipMemsetAsync(sums, 0, (2 * DIM + 512) * sizeof(int), stream);

  hist_kernel      <<<NPB, 256, 0, stream>>>(ei, gcount);
  scan_small_kernel<<<1, 512, 0, stream>>>(gcount, bucket_base, gcursor);
  partition_kernel <<<NPB, 256, 0, stream>>>(ei, gcursor, bpart);
  bucket_kernel    <<<NB, 256, 0, stream>>>(bpart, bucket_base, csr_src, row_start, row_end);
  gather_kernel    <<<N * 16 / 256, 256, 0, stream>>>(x, csr_src, row_start, row_end, agg);
  fused1_kernel    <<<(N + 255) / 256, 256, 0, stream>>>(x, agg, W1, b1, eps, N);
  stats_kernel     <<<512, 256, 0, stream>>>(agg, sums, sumsq, N);
  fused2_kernel    <<<(N + 255) / 256, 256, 0, stream>>>(agg, outp, W2, b2,
                                                         gamma, beta, sums, sumsq, N);
}

// Round 5
// 271.844 us; speedup vs baseline: 5.6758x; 1.1086x over previous
//
#include <hip/hip_runtime.h>

#define NNODES 100000
#define NEDGES 1600000
#define DIM 64
#define NB 391          // buckets of 256 nodes (dst >> 8)
#define NPB 200         // partition blocks
#define CHUNK 8000      // edges per partition block (NPB * CHUNK == NEDGES)
#define CAP 8192        // padded slots per bucket in bpart (Poisson(4096) + 64 sigma)

// ---------------- P0: init per-bucket cursors to padded bases ---------------
__global__ __launch_bounds__(512) void init_kernel(int* __restrict__ gcursor) {
  int t = threadIdx.x;
  if (t < NB) gcursor[t] = t * CAP;
}

// ---------------- P1: partition edges into padded buckets -------------------
__global__ __launch_bounds__(1024) void partition_kernel(
    const int* __restrict__ ei, int* __restrict__ gcursor,
    int* __restrict__ bpart) {
  __shared__ int lh[NB];
  __shared__ int cur[NB];
  int t = threadIdx.x;
  for (int b = t; b < NB; b += 1024) lh[b] = 0;
  __syncthreads();
  int base = blockIdx.x * CHUNK;
  for (int i = t; i < CHUNK; i += 1024)
    atomicAdd(&lh[ei[NEDGES + base + i] >> 8], 1);
  __syncthreads();
  for (int b = t; b < NB; b += 1024) {
    int c = lh[b];
    cur[b] = c ? atomicAdd(&gcursor[b], c) : 0;   // reserve contiguous run
  }
  __syncthreads();
  for (int i = t; i < CHUNK; i += 1024) {
    int s = ei[base + i];
    int d = ei[NEDGES + base + i];
    int p = atomicAdd(&cur[d >> 8], 1);
    bpart[p] = ((d & 255) << 17) | s;   // src < 2^17, dlow in bits 17..24
  }
}

// ---------------- P2: tiny scan -> compact CSR bases ------------------------
__global__ __launch_bounds__(512) void scan_small_kernel(
    const int* __restrict__ gcursor, int* __restrict__ bucket_base) {
  __shared__ int sd[512];
  int t = threadIdx.x;
  int v = (t < NB) ? (gcursor[t] - t * CAP) : 0;   // bucket count
  sd[t] = v;
  __syncthreads();
  for (int off = 1; off < 512; off <<= 1) {
    int a = (t >= off) ? sd[t - off] : 0;
    __syncthreads();
    sd[t] += a;
    __syncthreads();
  }
  bucket_base[t] = sd[t] - v;          // exclusive prefix; [NB] == NEDGES
}

// ---------------- P3: per-bucket counting sort, coalesced csr flush ---------
__global__ __launch_bounds__(1024) void bucket_kernel(
    const int* __restrict__ bpart, const int* __restrict__ gcursor,
    const int* __restrict__ bucket_base, int* __restrict__ csr_src,
    int* __restrict__ row_start, int* __restrict__ row_end) {
  __shared__ int sd[256];
  __shared__ int cur[256];
  __shared__ int stage[CAP];
  int b = blockIdx.x;
  int t = threadIdx.x;
  int pbase = b * CAP;                  // padded input base
  int cnt = gcursor[b] - pbase;
  int cbase = bucket_base[b];           // compact output base
  if (t < 256) sd[t] = 0;
  __syncthreads();
  for (int i = t; i < cnt; i += 1024)
    atomicAdd(&sd[bpart[pbase + i] >> 17], 1);
  __syncthreads();
  int deg = (t < 256) ? sd[t] : 0;
  for (int off = 1; off < 256; off <<= 1) {  // inclusive scan of degrees
    int a = (t < 256 && t >= off) ? sd[t - off] : 0;
    __syncthreads();
    if (t < 256) sd[t] += a;
    __syncthreads();
  }
  if (t < 256) {
    int excl = sd[t] - deg;
    int node = b * 256 + t;
    if (node < NNODES) {
      row_start[node] = cbase + excl;
      row_end[node] = cbase + excl + deg;
    }
    cur[t] = excl;
  }
  __syncthreads();
  for (int i = t; i < cnt; i += 1024) {
    int v = bpart[pbase + i];
    int p = atomicAdd(&cur[v >> 17], 1);
    stage[p] = v & 0x1FFFF;               // LDS scatter, cheap
  }
  __syncthreads();
  for (int i = t; i < cnt; i += 1024)
    csr_src[cbase + i] = stage[i];        // fully coalesced global flush
}

// ---------------- gather: agg[i] = sum_{e in row i} x[csr_src[e]] -----------
__global__ __launch_bounds__(256) void gather_kernel(
    const float* __restrict__ x, const int* __restrict__ csr_src,
    const int* __restrict__ row_start, const int* __restrict__ row_end,
    float* __restrict__ agg) {
  int tid = blockIdx.x * 256 + threadIdx.x;   // N*16 threads exactly
  int node = tid >> 4;
  int part = tid & 15;
  int e0 = row_start[node];
  int e1 = row_end[node];
  float4 a0 = make_float4(0.f, 0.f, 0.f, 0.f);
  float4 a1 = a0, a2 = a0, a3 = a0;
  int e = e0;
  for (; e + 4 <= e1; e += 4) {           // 4 independent loads in flight
    int s0 = csr_src[e + 0];
    int s1 = csr_src[e + 1];
    int s2 = csr_src[e + 2];
    int s3 = csr_src[e + 3];
    float4 v0 = ((const float4*)(x + (size_t)s0 * DIM))[part];
    float4 v1 = ((const float4*)(x + (size_t)s1 * DIM))[part];
    float4 v2 = ((const float4*)(x + (size_t)s2 * DIM))[part];
    float4 v3 = ((const float4*)(x + (size_t)s3 * DIM))[part];
    a0.x += v0.x; a0.y += v0.y; a0.z += v0.z; a0.w += v0.w;
    a1.x += v1.x; a1.y += v1.y; a1.z += v1.z; a1.w += v1.w;
    a2.x += v2.x; a2.y += v2.y; a2.z += v2.z; a2.w += v2.w;
    a3.x += v3.x; a3.y += v3.y; a3.z += v3.z; a3.w += v3.w;
  }
  for (; e < e1; ++e) {
    int s = csr_src[e];
    float4 v = ((const float4*)(x + (size_t)s * DIM))[part];
    a0.x += v.x; a0.y += v.y; a0.z += v.z; a0.w += v.w;
  }
  float4 acc;
  acc.x = (a0.x + a1.x) + (a2.x + a3.x);
  acc.y = (a0.y + a1.y) + (a2.y + a3.y);
  acc.z = (a0.z + a1.z) + (a2.z + a3.z);
  acc.w = (a0.w + a1.w) + (a2.w + a3.w);
  ((float4*)(agg + (size_t)node * DIM))[part] = acc;
}

// ---------------- fused1: h1 = ((1+eps)*x + agg) @ W1 + b1 (in-place) -------
__global__ __launch_bounds__(256) void fused1_kernel(
    const float* __restrict__ x, float* __restrict__ h1,
    const float* __restrict__ W1, const float* __restrict__ b1,
    const float* __restrict__ epsp, int N) {
  __shared__ float Ws[DIM * DIM];
  __shared__ float bs[DIM];
  for (int t = threadIdx.x; t < DIM * DIM / 4; t += 256)
    ((float4*)Ws)[t] = ((const float4*)W1)[t];
  if (threadIdx.x < DIM / 4)
    ((float4*)bs)[threadIdx.x] = ((const float4*)b1)[threadIdx.x];
  __syncthreads();
  int i = blockIdx.x * 256 + threadIdx.x;
  if (i >= N) return;
  float onep = 1.0f + epsp[0];
  float h[DIM];
  const float4* xr = (const float4*)(x + (size_t)i * DIM);
  float4* ar = (float4*)(h1 + (size_t)i * DIM);
#pragma unroll
  for (int k4 = 0; k4 < 16; ++k4) {
    float4 a = xr[k4];
    float4 g = ar[k4];
    h[k4 * 4 + 0] = fmaf(onep, a.x, g.x);
    h[k4 * 4 + 1] = fmaf(onep, a.y, g.y);
    h[k4 * 4 + 2] = fmaf(onep, a.z, g.z);
    h[k4 * 4 + 3] = fmaf(onep, a.w, g.w);
  }
#pragma unroll 1
  for (int jt = 0; jt < DIM; jt += 16) {
    float acc[16];
#pragma unroll
    for (int q = 0; q < 4; ++q) {
      float4 b = ((const float4*)&bs[jt])[q];
      acc[q * 4 + 0] = b.x;
      acc[q * 4 + 1] = b.y;
      acc[q * 4 + 2] = b.z;
      acc[q * 4 + 3] = b.w;
    }
#pragma unroll
    for (int k = 0; k < DIM; ++k) {
      float hk = h[k];
      const float4* wr = (const float4*)&Ws[k * DIM + jt];
#pragma unroll
      for (int q = 0; q < 4; ++q) {
        float4 w = wr[q];
        acc[q * 4 + 0] = fmaf(hk, w.x, acc[q * 4 + 0]);
        acc[q * 4 + 1] = fmaf(hk, w.y, acc[q * 4 + 1]);
        acc[q * 4 + 2] = fmaf(hk, w.z, acc[q * 4 + 2]);
        acc[q * 4 + 3] = fmaf(hk, w.w, acc[q * 4 + 3]);
      }
    }
    float4* orow = (float4*)(h1 + (size_t)i * DIM + jt);
#pragma unroll
    for (int q = 0; q < 4; ++q)
      orow[q] = make_float4(acc[q * 4 + 0], acc[q * 4 + 1],
                            acc[q * 4 + 2], acc[q * 4 + 3]);
  }
}

// ---------------- BN stats: per-column sum and sumsq over N rows ------------
__global__ __launch_bounds__(256) void stats_kernel(
    const float* __restrict__ h1, float* __restrict__ sums,
    float* __restrict__ sumsq, int N) {
  int j = threadIdx.x & 63;
  int rsub = threadIdx.x >> 6;  // 0..3
  float s = 0.0f, q = 0.0f;
  for (int r = blockIdx.x * 4 + rsub; r < N; r += gridDim.x * 4) {
    float v = h1[(size_t)r * DIM + j];
    s += v;
    q = fmaf(v, v, q);
  }
  __shared__ float ls[256];
  __shared__ float lq[256];
  ls[threadIdx.x] = s;
  lq[threadIdx.x] = q;
  __syncthreads();
  if (threadIdx.x < 64) {
    s = ls[j] + ls[j + 64] + ls[j + 128] + ls[j + 192];
    q = lq[j] + lq[j + 64] + lq[j + 128] + lq[j + 192];
    atomicAdd(&sums[j], s);
    atomicAdd(&sumsq[j], q);
  }
}

// ---------------- fused2: out = relu(bn(h1)) @ W2 + b2 ----------------------
__global__ __launch_bounds__(256) void fused2_kernel(
    const float* __restrict__ h1, float* __restrict__ out,
    const float* __restrict__ W2, const float* __restrict__ b2,
    const float* __restrict__ gamma, const float* __restrict__ beta,
    const float* __restrict__ sums, const float* __restrict__ sumsq, int N) {
  __shared__ float Ws[DIM * DIM];
  __shared__ float bs[DIM];
  __shared__ float sc_s[DIM];
  __shared__ float sh_s[DIM];
  for (int t = threadIdx.x; t < DIM * DIM / 4; t += 256)
    ((float4*)Ws)[t] = ((const float4*)W2)[t];
  if (threadIdx.x < DIM / 4)
    ((float4*)bs)[threadIdx.x] = ((const float4*)b2)[threadIdx.x];
  if (threadIdx.x >= 64 && threadIdx.x < 128) {
    int j = threadIdx.x - 64;
    float invN = 1.0f / (float)N;
    float m = sums[j] * invN;
    float v = fmaf(-m, m, sumsq[j] * invN);
    float sc = gamma[j] * rsqrtf(v + 1e-5f);
    sc_s[j] = sc;
    sh_s[j] = fmaf(-m, sc, beta[j]);
  }
  __syncthreads();
  int i = blockIdx.x * 256 + threadIdx.x;
  if (i >= N) return;
  float h[DIM];
  const float4* hr = (const float4*)(h1 + (size_t)i * DIM);
#pragma unroll
  for (int k4 = 0; k4 < 16; ++k4) {
    float4 a = hr[k4];
    float4 sc = ((const float4*)sc_s)[k4];
    float4 sh = ((const float4*)sh_s)[k4];
    h[k4 * 4 + 0] = fmaxf(fmaf(a.x, sc.x, sh.x), 0.0f);
    h[k4 * 4 + 1] = fmaxf(fmaf(a.y, sc.y, sh.y), 0.0f);
    h[k4 * 4 + 2] = fmaxf(fmaf(a.z, sc.z, sh.z), 0.0f);
    h[k4 * 4 + 3] = fmaxf(fmaf(a.w, sc.w, sh.w), 0.0f);
  }
#pragma unroll 1
  for (int jt = 0; jt < DIM; jt += 16) {
    float acc[16];
#pragma unroll
    for (int q = 0; q < 4; ++q) {
      float4 b = ((const float4*)&bs[jt])[q];
      acc[q * 4 + 0] = b.x;
      acc[q * 4 + 1] = b.y;
      acc[q * 4 + 2] = b.z;
      acc[q * 4 + 3] = b.w;
    }
#pragma unroll
    for (int k = 0; k < DIM; ++k) {
      float hk = h[k];
      const float4* wr = (const float4*)&Ws[k * DIM + jt];
#pragma unroll
      for (int q = 0; q < 4; ++q) {
        float4 w = wr[q];
        acc[q * 4 + 0] = fmaf(hk, w.x, acc[q * 4 + 0]);
        acc[q * 4 + 1] = fmaf(hk, w.y, acc[q * 4 + 1]);
        acc[q * 4 + 2] = fmaf(hk, w.z, acc[q * 4 + 2]);
        acc[q * 4 + 3] = fmaf(hk, w.w, acc[q * 4 + 3]);
      }
    }
    float4* orow = (float4*)(out + (size_t)i * DIM + jt);
#pragma unroll
    for (int q = 0; q < 4; ++q)
      orow[q] = make_float4(acc[q * 4 + 0], acc[q * 4 + 1],
                            acc[q * 4 + 2], acc[q * 4 + 3]);
  }
}

extern "C" void kernel_launch(void* const* d_in, const int* in_sizes, int n_in,
                              void* d_out, int out_size, void* d_ws, size_t ws_size,
                              hipStream_t stream) {
  (void)in_sizes; (void)n_in; (void)out_size; (void)ws_size;
  const float* x     = (const float*)d_in[0];
  const int*   ei    = (const int*)d_in[1];
  const float* eps   = (const float*)d_in[2];
  const float* W1    = (const float*)d_in[3];
  const float* b1    = (const float*)d_in[4];
  const float* gamma = (const float*)d_in[5];
  const float* beta  = (const float*)d_in[6];
  const float* W2    = (const float*)d_in[7];
  const float* b2    = (const float*)d_in[8];
  float* outp = (float*)d_out;

  const int N = NNODES;

  // workspace layout (~32.8 MB)
  float* agg        = (float*)d_ws;                  // N*64 f32 (reused as h1)
  float* sums       = agg + (size_t)N * DIM;         // 64 f32   (zeroed)
  float* sumsq      = sums + DIM;                    // 64 f32   (zeroed)
  int*   gcursor    = (int*)(sumsq + DIM);           // 512 int
  int*   bucket_base= gcursor + 512;                 // 512 int
  int*   row_start  = bucket_base + 512;             // N int
  int*   row_end    = row_start + NNODES;            // N int
  int*   csr_src    = row_end + NNODES;              // NEDGES int (compact)
  int*   bpart      = (int*)agg;                     // NB*CAP int, aliases agg
                                                     // (dead before gather writes agg)

  hipMemsetAsync(sums, 0, 2 * DIM * sizeof(float), stream);

  init_kernel      <<<1, 512, 0, stream>>>(gcursor);
  partition_kernel <<<NPB, 1024, 0, stream>>>(ei, gcursor, bpart);
  scan_small_kernel<<<1, 512, 0, stream>>>(gcursor, bucket_base);
  bucket_kernel    <<<NB, 1024, 0, stream>>>(bpart, gcursor, bucket_base,
                                             csr_src, row_start, row_end);
  gather_kernel    <<<N * 16 / 256, 256, 0, stream>>>(x, csr_src, row_start, row_end, agg);
  fused1_kernel    <<<(N + 255) / 256, 256, 0, stream>>>(x, agg, W1, b1, eps, N);
  stats_kernel     <<<512, 256, 0, stream>>>(agg, sums, sumsq, N);
  fused2_kernel    <<<(N + 255) / 256, 256, 0, stream>>>(agg, outp, W2, b2,
                                                         gamma, beta, sums, sumsq, N);
}